// Round 1
// baseline (3314.881 us; speedup 1.0000x reference)
//
#include <hip/hip_runtime.h>
#include <math.h>

// Problem constants
// S=16, B=128, FEAT=2048, HAND=63, H=1024, C=1000
// Only t=S-1 contributes to the output: out = (h after 2 unroll steps from
// (hs[15],cs[15]) with xt=x[15]) @ cls_w.T + cls_b.

// ---------------------------------------------------------------------------
// Generic f32 GEMM: C[M x N] = concat_k(A1,A2) @ concat_k(W1,W2)^T
//                              + b1 (+ b2) (+ Cinit)
// BM=32, BN=64, BK=32, 256 threads, per-thread 2x4 microtile.
// LDS stored transposed [kk][row] so inner loop reads are float2/float4.
// M must be a multiple of 32, K1 and K2 multiples of 32 (or K2==0).
// ---------------------------------------------------------------------------
__global__ __launch_bounds__(256)
void gemm_f32(const float* __restrict__ A1, int lda1, int K1,
              const float* __restrict__ A2, int lda2, int K2,
              const float* __restrict__ W1, const float* __restrict__ W2,
              const float* __restrict__ b1, const float* __restrict__ b2,
              const float* __restrict__ Cinit,
              float* __restrict__ C, int M, int N, int ldc)
{
    __shared__ float As[32][34];   // [kk][r], pad 2 keeps float2 aligned
    __shared__ float Ws[32][68];   // [kk][n], pad 4 keeps float4 aligned
    const int tid = threadIdx.x;
    const int bn = blockIdx.x * 64;
    const int bm = blockIdx.y * 32;
    const int ty = tid >> 4;       // 0..15 -> rows ty*2, ty*2+1
    const int tx = tid & 15;       // 0..15 -> cols tx*4 .. tx*4+3
    const int K = K1 + K2;

    float acc[2][4] = {{0.f,0.f,0.f,0.f},{0.f,0.f,0.f,0.f}};

    const int lr = tid >> 3;          // 0..31
    const int lk = (tid & 7) << 2;    // 0,4,...,28

    for (int k0 = 0; k0 < K; k0 += 32) {
        // ---- stage A tile (rows bm..bm+31) ----
        {
            const int k = k0 + lk;
            const float* src = (k < K1)
                ? (A1 + (size_t)(bm + lr) * lda1 + k)
                : (A2 + (size_t)(bm + lr) * lda2 + (k - K1));
            float4 v = *reinterpret_cast<const float4*>(src);
            As[lk+0][lr] = v.x; As[lk+1][lr] = v.y;
            As[lk+2][lr] = v.z; As[lk+3][lr] = v.w;
        }
        // ---- stage W tile (output cols bn..bn+63) ----
        #pragma unroll
        for (int i = 0; i < 2; ++i) {
            const int n = bn + lr + 32 * i;
            const int k = k0 + lk;
            float4 v = make_float4(0.f, 0.f, 0.f, 0.f);
            if (n < N) {
                const float* src = (k < K1)
                    ? (W1 + (size_t)n * K1 + k)
                    : (W2 + (size_t)n * K2 + (k - K1));
                v = *reinterpret_cast<const float4*>(src);
            }
            Ws[lk+0][lr + 32*i] = v.x; Ws[lk+1][lr + 32*i] = v.y;
            Ws[lk+2][lr + 32*i] = v.z; Ws[lk+3][lr + 32*i] = v.w;
        }
        __syncthreads();
        #pragma unroll
        for (int kk = 0; kk < 32; ++kk) {
            float2 a = *reinterpret_cast<const float2*>(&As[kk][ty * 2]);
            float4 w = *reinterpret_cast<const float4*>(&Ws[kk][tx * 4]);
            acc[0][0] = fmaf(a.x, w.x, acc[0][0]);
            acc[0][1] = fmaf(a.x, w.y, acc[0][1]);
            acc[0][2] = fmaf(a.x, w.z, acc[0][2]);
            acc[0][3] = fmaf(a.x, w.w, acc[0][3]);
            acc[1][0] = fmaf(a.y, w.x, acc[1][0]);
            acc[1][1] = fmaf(a.y, w.y, acc[1][1]);
            acc[1][2] = fmaf(a.y, w.z, acc[1][2]);
            acc[1][3] = fmaf(a.y, w.w, acc[1][3]);
        }
        __syncthreads();
    }

    const int row0 = bm + ty * 2;
    #pragma unroll
    for (int j = 0; j < 4; ++j) {
        const int n = bn + tx * 4 + j;
        if (n < N) {
            const float bias = b1[n] + (b2 ? b2[n] : 0.f);
            #pragma unroll
            for (int r = 0; r < 2; ++r) {
                const size_t off = (size_t)(row0 + r) * ldc + n;
                float v = acc[r][j] + bias;
                if (Cinit) v += Cinit[off];
                C[off] = v;
            }
        }
    }
}

// ---------------------------------------------------------------------------
// hproj: x[:, 1024:2048] = concat(lh, rh) @ fch_w^T + fch_b   (K = 126)
// One block handles 16 rows; 128 blocks total.
// ---------------------------------------------------------------------------
__global__ __launch_bounds__(256)
void hproj_kernel(const float* __restrict__ lh, const float* __restrict__ rh,
                  const float* __restrict__ fchw, const float* __restrict__ fchb,
                  float* __restrict__ x)
{
    __shared__ float hs[16][126];
    const int brow = blockIdx.x * 16;
    for (int idx = threadIdx.x; idx < 16 * 126; idx += 256) {
        const int r = idx / 126, k = idx % 126;
        const int grow = brow + r;
        hs[r][k] = (k < 63) ? lh[(size_t)grow * 63 + k]
                            : rh[(size_t)grow * 63 + (k - 63)];
    }
    __syncthreads();
    for (int j = threadIdx.x; j < 1024; j += 256) {
        float acc[16];
        #pragma unroll
        for (int r = 0; r < 16; ++r) acc[r] = 0.f;
        const float* wrow = fchw + (size_t)j * 126;
        for (int k = 0; k < 126; ++k) {
            const float w = wrow[k];
            #pragma unroll
            for (int r = 0; r < 16; ++r) acc[r] = fmaf(w, hs[r][k], acc[r]);
        }
        const float b = fchb[j];
        #pragma unroll
        for (int r = 0; r < 16; ++r)
            x[(size_t)(brow + r) * 2048 + 1024 + j] = acc[r] + b;
    }
}

// ---------------------------------------------------------------------------
// LSTM cell elementwise: gates (128 x 4096, order i|f|g|o), updates h,c.
// ---------------------------------------------------------------------------
__global__ __launch_bounds__(256)
void lstm_cell(const float* __restrict__ gates,
               float* __restrict__ h, float* __restrict__ c)
{
    const int idx = blockIdx.x * 256 + threadIdx.x;
    if (idx >= 128 * 1024) return;
    const int b = idx >> 10, j = idx & 1023;
    const float* g = gates + (size_t)b * 4096;
    const float ig = g[j];
    const float fg = g[1024 + j];
    const float gg = g[2048 + j];
    const float og = g[3072 + j];
    const float si = 1.f / (1.f + __expf(-ig));
    const float sf = 1.f / (1.f + __expf(-fg));
    const float so = 1.f / (1.f + __expf(-og));
    const float tg = tanhf(gg);
    const float cn = sf * c[idx] + si * tg;
    const float hn = so * tanhf(cn);
    c[idx] = cn;
    h[idx] = hn;
}

// ---------------------------------------------------------------------------
// Head: per-batch argmax (first-index tie-break) + logsumexp + per-b loss.
// ---------------------------------------------------------------------------
__global__ __launch_bounds__(256)
void head_kernel(const float* __restrict__ logits, const int* __restrict__ act,
                 float* __restrict__ d_out, float* __restrict__ lossbuf)
{
    const int b = blockIdx.x;
    const int tid = threadIdx.x;
    const float* row = logits + (size_t)b * 1000;

    float mx = -1e30f; int mi = 1 << 30;
    for (int j = tid; j < 1000; j += 256) {
        const float v = row[j];
        if (v > mx) { mx = v; mi = j; }   // strict > keeps the first max
    }
    __shared__ float smx[256];
    __shared__ int   smi[256];
    smx[tid] = mx; smi[tid] = mi;
    __syncthreads();
    for (int s = 128; s > 0; s >>= 1) {
        if (tid < s) {
            const float v2 = smx[tid + s]; const int i2 = smi[tid + s];
            if (v2 > smx[tid] || (v2 == smx[tid] && i2 < smi[tid])) {
                smx[tid] = v2; smi[tid] = i2;
            }
        }
        __syncthreads();
    }
    const float gmx = smx[0];
    const int   gmi = smi[0];
    __syncthreads();

    float partial = 0.f;
    for (int j = tid; j < 1000; j += 256) partial += __expf(row[j] - gmx);
    smx[tid] = partial;
    __syncthreads();
    for (int s = 128; s > 0; s >>= 1) {
        if (tid < s) smx[tid] += smx[tid + s];
        __syncthreads();
    }
    if (tid == 0) {
        d_out[128000 + b] = (float)gmi;
        lossbuf[b] = gmx + logf(smx[0]) - row[act[b]];
    }
}

__global__ __launch_bounds__(128)
void loss_reduce(const float* __restrict__ lossbuf, float* __restrict__ d_out)
{
    __shared__ float s[128];
    const int tid = threadIdx.x;
    s[tid] = lossbuf[tid];
    __syncthreads();
    for (int k = 64; k > 0; k >>= 1) {
        if (tid < k) s[tid] += s[tid + k];
        __syncthreads();
    }
    if (tid == 0) d_out[128128] = s[0] / 128.f;
}

// ---------------------------------------------------------------------------
extern "C" void kernel_launch(void* const* d_in, const int* in_sizes, int n_in,
                              void* d_out, int out_size, void* d_ws, size_t ws_size,
                              hipStream_t stream)
{
    const float* feats    = (const float*)d_in[0];
    const float* lh       = (const float*)d_in[1];
    const float* rh       = (const float*)d_in[2];
    const int*   act      = (const int*)  d_in[3];
    const float* fc1_w    = (const float*)d_in[4];
    const float* fc1_b    = (const float*)d_in[5];
    const float* fch_w    = (const float*)d_in[6];
    const float* fch_b    = (const float*)d_in[7];
    const float* roll_wih = (const float*)d_in[8];
    const float* roll_whh = (const float*)d_in[9];
    const float* roll_bih = (const float*)d_in[10];
    const float* roll_bhh = (const float*)d_in[11];
    const float* un_wih   = (const float*)d_in[12];
    const float* un_whh   = (const float*)d_in[13];
    const float* un_bih   = (const float*)d_in[14];
    const float* un_bhh   = (const float*)d_in[15];
    const float* cls_w    = (const float*)d_in[16];
    const float* cls_b    = (const float*)d_in[17];

    float* out = (float*)d_out;

    // workspace layout (floats)
    float* x       = (float*)d_ws;            // 2048*2048  (x = [xproj | hproj])
    float* gates   = x     + 2048 * 2048;     // 128*4096
    float* xgate   = gates + 128 * 4096;      // 128*4096
    float* h       = xgate + 128 * 4096;      // 128*1024
    float* c       = h     + 128 * 1024;      // 128*1024
    float* lossbuf = c     + 128 * 1024;      // 128

    // h and c are contiguous -> one async memset (graph-capture safe)
    hipMemsetAsync(h, 0, (size_t)2 * 128 * 1024 * sizeof(float), stream);

    // x[:, :1024] = feats @ fc1_w^T + fc1_b     (M=2048, K=2048, N=1024)
    gemm_f32<<<dim3(1024 / 64, 2048 / 32), 256, 0, stream>>>(
        feats, 2048, 2048, nullptr, 0, 0,
        fc1_w, nullptr, fc1_b, nullptr, nullptr,
        x, 2048, 1024, 2048);

    // x[:, 1024:] = hands @ fch_w^T + fch_b
    hproj_kernel<<<128, 256, 0, stream>>>(lh, rh, fch_w, fch_b, x);

    // rolling LSTM: 16 sequential steps; (h,c) ends as (hs[15], cs[15])
    for (int t = 0; t < 16; ++t) {
        gemm_f32<<<dim3(4096 / 64, 128 / 32), 256, 0, stream>>>(
            x + (size_t)t * 128 * 2048, 2048, 2048,
            h, 1024, 1024,
            roll_wih, roll_whh, roll_bih, roll_bhh, nullptr,
            gates, 128, 4096, 4096);
        lstm_cell<<<512, 256, 0, stream>>>(gates, h, c);
    }

    // unroll input-gate term (step-invariant): xgate = x[15] @ un_wih^T + un_bih
    gemm_f32<<<dim3(4096 / 64, 128 / 32), 256, 0, stream>>>(
        x + (size_t)15 * 128 * 2048, 2048, 2048, nullptr, 0, 0,
        un_wih, nullptr, un_bih, nullptr, nullptr,
        xgate, 128, 4096, 4096);

    // two unroll steps (h_n[S-1] = hseq[1] = h after 2 steps)
    for (int s = 0; s < 2; ++s) {
        gemm_f32<<<dim3(4096 / 64, 128 / 32), 256, 0, stream>>>(
            h, 1024, 1024, nullptr, 0, 0,
            un_whh, nullptr, un_bhh, nullptr, xgate,
            gates, 128, 4096, 4096);
        lstm_cell<<<512, 256, 0, stream>>>(gates, h, c);
    }

    // classifier: out = h @ cls_w^T + cls_b    (128 x 1000) -> d_out[0:128000)
    gemm_f32<<<dim3((1000 + 63) / 64, 128 / 32), 256, 0, stream>>>(
        h, 1024, 1024, nullptr, 0, 0,
        cls_w, nullptr, cls_b, nullptr, nullptr,
        out, 128, 1000, 1000);

    // pred (as float) -> d_out[128000:128128), per-b loss -> lossbuf
    head_kernel<<<128, 256, 0, stream>>>(out, act, out, lossbuf);
    // loss mean -> d_out[128128]
    loss_reduce<<<1, 128, 0, stream>>>(lossbuf, out);
}

// Round 3
// 740.304 us; speedup vs baseline: 4.4777x; 4.4777x over previous
//
#include <hip/hip_runtime.h>
#include <math.h>

// S=16, B=128, FEAT=2048, HAND=63, H=1024, C=1000
// out depends only on t=S-1 => 2 unroll steps from (hs[15], cs[15]).
// gates(t) = [x_t @ wih^T + bih + bhh] (hoisted) + h @ whh^T
//
// Precision scheme: every GEMM operand is double-f16 (hi + lo), and each
// GEMM accumulates 3 segments in f32: Ahi*Whi + Alo*Whi + Ahi*Wlo.
// Buffers store rows as [hi(K) | lo(K)]; the segment loop offsets pointers.

typedef __attribute__((ext_vector_type(8))) _Float16 f16x8;
typedef __attribute__((ext_vector_type(4))) _Float16 f16x4;
typedef __attribute__((ext_vector_type(4))) float     f32x4;

typedef __attribute__((address_space(1))) const void as1c_void;
typedef __attribute__((address_space(3))) void       as3_void;
#define GLOAD_LDS16(g, l) \
    __builtin_amdgcn_global_load_lds((as1c_void*)(g), (as3_void*)(l), 16, 0, 0)

// ---------------------------------------------------------------------------
// MFMA GEMM with 3-segment double-f16 accumulation.
// A: f16 [M][lda], split rows [hi|lo], lo at +aLoOff elements.
// W: WF32=false -> f16 [N][ldw] split rows, lo at +wLoOff.
//    WF32=true  -> f32 [N][ldw] raw; staging converts (seg<2: hi, seg2: lo).
// BM=128, BK=64, 4 waves (2x2), wave tile 64 x (BN/2).
// LDS XOR-swizzle byte^=((row&7)<<4) via pre-swizzled source address.
// grid.z = K-split: slice [z*ksize, (z+1)*ksize), partial to Cf+z*cOffPerZ.
// OUTMODE: 0 = f32, 1 = f16 split (hi at col, lo at col+ldc/2).
// ---------------------------------------------------------------------------
template<int BN, int OUTMODE, bool BIAS, bool WF32>
__global__ __launch_bounds__(256)
void gemm_mfma(const _Float16* __restrict__ A, int lda, int aLoOff,
               const void* __restrict__ Wp, int ldw, int wLoOff,
               const float* __restrict__ bias,
               void* __restrict__ Cout, int ldc, int Nout,
               int ksize, long cOffPerZ)
{
    static_assert(!WF32 || BN == 64, "WF32 staging assumes BN==64");
    constexpr int BM = 128, BK = 64;
    constexpr int WTN = BN / 2;
    constexpr int NF  = WTN / 16;

    __shared__ _Float16 As[BM * BK];
    __shared__ _Float16 Ws[BN * BK];

    const int tid  = threadIdx.x;
    const int wave = tid >> 6, lane = tid & 63;
    const int wr = wave >> 1, wc = wave & 1;
    const int bn = blockIdx.x * BN;
    const int bm = blockIdx.y * BM;
    const long kbase = (long)blockIdx.z * ksize;

    f32x4 acc[4][NF];
    #pragma unroll
    for (int i = 0; i < 4; ++i)
        #pragma unroll
        for (int j = 0; j < NF; ++j) acc[i][j] = (f32x4){0.f, 0.f, 0.f, 0.f};

    const int srow  = tid >> 3;          // 0..31
    const int sbyte = (tid & 7) * 16;
    const int swzS  = (srow & 7) << 4;

    const int arow0 = wr * 64 + (lane & 15);
    const int abyte = (lane >> 4) * 16;

    for (int seg = 0; seg < 3; ++seg) {
        const int aOff = (seg == 1) ? aLoOff : 0;
        const int wOff = (seg == 2) ? wLoOff : 0;
        const bool wlo = (seg == 2);

        for (int k0 = 0; k0 < ksize; k0 += BK) {
            const long kg = kbase + k0;
            // ---- stage A: linear LDS dest, pre-swizzled global source ----
            #pragma unroll
            for (int r = 0; r < 4; ++r) {
                const _Float16* src = A + ((long)(bm + 32*r + srow) * lda
                                           + aOff + kg) + ((sbyte ^ swzS) >> 1);
                GLOAD_LDS16(src, (char*)As + r*4096 + wave*1024);
            }
            // ---- stage W ----
            if constexpr (!WF32) {
                const _Float16* W = (const _Float16*)Wp;
                #pragma unroll
                for (int r = 0; r < BN/32; ++r) {
                    const _Float16* src = W + ((long)(bn + 32*r + srow) * ldw
                                               + wOff + kg) + ((sbyte ^ swzS) >> 1);
                    GLOAD_LDS16(src, (char*)Ws + r*4096 + wave*1024);
                }
            } else {
                const float* W = (const float*)Wp;
                const int rw = tid >> 2;
                const int eb = (tid & 3) * 16;
                int wn = bn + rw; if (wn > Nout - 1) wn = Nout - 1;
                const float* src = W + (long)wn * ldw + kg + eb;
                float4 v0 = *(const float4*)(src);
                float4 v1 = *(const float4*)(src + 4);
                float4 v2 = *(const float4*)(src + 8);
                float4 v3 = *(const float4*)(src + 12);
                float vv[16] = {v0.x,v0.y,v0.z,v0.w, v1.x,v1.y,v1.z,v1.w,
                                v2.x,v2.y,v2.z,v2.w, v3.x,v3.y,v3.z,v3.w};
                f16x8 o0, o1;
                #pragma unroll
                for (int e = 0; e < 8; ++e) {
                    _Float16 h0 = (_Float16)vv[e];
                    _Float16 h1 = (_Float16)vv[8 + e];
                    o0[e] = wlo ? (_Float16)(vv[e]     - (float)h0) : h0;
                    o1[e] = wlo ? (_Float16)(vv[8 + e] - (float)h1) : h1;
                }
                const int swzW = (rw & 7) << 4;
                *(f16x8*)((char*)Ws + rw*128 + ((eb*2)      ^ swzW)) = o0;
                *(f16x8*)((char*)Ws + rw*128 + ((eb*2 + 16) ^ swzW)) = o1;
            }
            __syncthreads();
            // ---- compute: 2 k-chunks of 32 ----
            #pragma unroll
            for (int kk = 0; kk < 2; ++kk) {
                f16x8 af[4], bfr[NF];
                #pragma unroll
                for (int mi = 0; mi < 4; ++mi) {
                    const int row = arow0 + mi*16;
                    const int byi = (kk*64 + abyte) ^ ((row & 7) << 4);
                    af[mi] = *(const f16x8*)((const char*)As + row*128 + byi);
                }
                #pragma unroll
                for (int ni = 0; ni < NF; ++ni) {
                    const int row = wc*WTN + ni*16 + (lane & 15);
                    const int byi = (kk*64 + abyte) ^ ((row & 7) << 4);
                    bfr[ni] = *(const f16x8*)((const char*)Ws + row*128 + byi);
                }
                #pragma unroll
                for (int mi = 0; mi < 4; ++mi)
                    #pragma unroll
                    for (int ni = 0; ni < NF; ++ni)
                        acc[mi][ni] = __builtin_amdgcn_mfma_f32_16x16x32_f16(
                            af[mi], bfr[ni], acc[mi][ni], 0, 0, 0);
            }
            __syncthreads();
        }
    }

    // ---- epilogue: C/D map col=lane&15, row=(lane>>4)*4+r ----
    float*     Cf = (float*)Cout + blockIdx.z * cOffPerZ;
    _Float16*  Ch = (_Float16*)Cout;
    #pragma unroll
    for (int mi = 0; mi < 4; ++mi) {
        #pragma unroll
        for (int ni = 0; ni < NF; ++ni) {
            const int col = bn + wc*WTN + ni*16 + (lane & 15);
            if (col < Nout) {
                const float bv = BIAS ? bias[col] : 0.f;
                #pragma unroll
                for (int r = 0; r < 4; ++r) {
                    const int row = bm + wr*64 + mi*16 + (lane >> 4)*4 + r;
                    const float v = acc[mi][ni][r] + bv;
                    if constexpr (OUTMODE == 1) {
                        _Float16 hi = (_Float16)v;
                        Ch[(long)row * ldc + col]           = hi;
                        Ch[(long)row * ldc + ldc/2 + col]   = (_Float16)(v - (float)hi);
                    } else {
                        Cf[(long)row * ldc + col] = v;
                    }
                }
            }
        }
    }
}

// ---------------------------------------------------------------------------
// f32 -> double-f16 split for reused tensors, rows become [hi(K)|lo(K)].
// vec4 ranges: feats 1048576 (K4=512) | roll_wih 2097152 (K4=512) |
// roll_whh 1048576 (K4=256). total 4194304 -> grid 16384 x 256.
// ---------------------------------------------------------------------------
__global__ __launch_bounds__(256)
void convert_split(const float* __restrict__ f0, const float* __restrict__ f1,
                   const float* __restrict__ f2,
                   _Float16* __restrict__ d0, _Float16* __restrict__ d1,
                   _Float16* __restrict__ d2)
{
    const long i = (long)blockIdx.x * 256 + threadIdx.x;
    const float* s; _Float16* d; long off, row, k4; int K4;
    if (i < 1048576)      { s = f0; d = d0; off = i;           K4 = 512; row = off >> 9; }
    else if (i < 3145728) { s = f1; d = d1; off = i - 1048576; K4 = 512; row = off >> 9; }
    else                  { s = f2; d = d2; off = i - 3145728; K4 = 256; row = off >> 8; }
    k4 = off - row * K4;
    const float4 v = ((const float4*)s)[off];
    f16x4 hi, lo;
    const float vv[4] = {v.x, v.y, v.z, v.w};
    #pragma unroll
    for (int j = 0; j < 4; ++j) {
        hi[j] = (_Float16)vv[j];
        lo[j] = (_Float16)(vv[j] - (float)hi[j]);
    }
    ((f16x4*)d)[row * 2 * K4 + k4]      = hi;
    ((f16x4*)d)[row * 2 * K4 + K4 + k4] = lo;
}

__global__ __launch_bounds__(256)
void bias_sum(const float* __restrict__ a1, const float* __restrict__ b1,
              const float* __restrict__ a2, const float* __restrict__ b2,
              float* __restrict__ o1, float* __restrict__ o2)
{
    const int i = blockIdx.x * 256 + threadIdx.x;
    if (i < 4096) { o1[i] = a1[i] + b1[i]; o2[i] = a2[i] + b2[i]; }
}

// ---------------------------------------------------------------------------
// hproj: x[:, 1024:2048] = concat(lh,rh) @ fch_w^T + fch_b  (K=126), f32 math,
// split-f16 output into x'' rows [hi(2048)|lo(2048)] (stride 4096).
// ---------------------------------------------------------------------------
__global__ __launch_bounds__(256)
void hproj_kernel(const float* __restrict__ lh, const float* __restrict__ rh,
                  const float* __restrict__ fchw, const float* __restrict__ fchb,
                  _Float16* __restrict__ x)
{
    __shared__ float hs[16][126];
    const int brow = blockIdx.x * 16;
    for (int idx = threadIdx.x; idx < 16 * 126; idx += 256) {
        const int r = idx / 126, k = idx % 126;
        const int grow = brow + r;
        hs[r][k] = (k < 63) ? lh[(long)grow * 63 + k]
                            : rh[(long)grow * 63 + (k - 63)];
    }
    __syncthreads();
    for (int j = threadIdx.x; j < 1024; j += 256) {
        float acc[16];
        #pragma unroll
        for (int r = 0; r < 16; ++r) acc[r] = 0.f;
        const float* wrow = fchw + (long)j * 126;
        for (int k = 0; k < 126; ++k) {
            const float w = wrow[k];
            #pragma unroll
            for (int r = 0; r < 16; ++r) acc[r] = fmaf(w, hs[r][k], acc[r]);
        }
        const float b = fchb[j];
        #pragma unroll
        for (int r = 0; r < 16; ++r) {
            const float v = acc[r] + b;
            const _Float16 hi = (_Float16)v;
            x[(long)(brow + r) * 4096 + 1024 + j] = hi;
            x[(long)(brow + r) * 4096 + 3072 + j] = (_Float16)(v - (float)hi);
        }
    }
}

// ---------------------------------------------------------------------------
// Fused LSTM cell: gates = xg(f32, incl biases) + sum of 4 K-split partials.
// Updates c (f32) and h'' (split f16 rows [hi(1024)|lo(1024)], stride 2048).
// ---------------------------------------------------------------------------
__global__ __launch_bounds__(256)
void lstm_cell4(const float* __restrict__ part, const float* __restrict__ xg,
                float* __restrict__ c, _Float16* __restrict__ h)
{
    const int t = blockIdx.x * 256 + threadIdx.x;
    const int b = t >> 8;
    const int j4 = (t & 255) << 2;
    const long base = (long)b * 4096;
    float4 g[4];
    #pragma unroll
    for (int q = 0; q < 4; ++q) {
        const long o = base + q*1024 + j4;
        float4 s = *(const float4*)(xg + o);
        #pragma unroll
        for (int p = 0; p < 4; ++p) {
            const float4 v = *(const float4*)(part + (long)p*524288 + o);
            s.x += v.x; s.y += v.y; s.z += v.z; s.w += v.w;
        }
        g[q] = s;
    }
    const long co = (long)b*1024 + j4;
    float4 cc = *(const float4*)(c + co);
    float cn[4], hn[4];
    const float* gi = (const float*)&g[0];
    const float* gf = (const float*)&g[1];
    const float* gg = (const float*)&g[2];
    const float* go = (const float*)&g[3];
    const float* cp = (const float*)&cc;
    #pragma unroll
    for (int k = 0; k < 4; ++k) {
        const float si = 1.f / (1.f + __expf(-gi[k]));
        const float sf = 1.f / (1.f + __expf(-gf[k]));
        const float so = 1.f / (1.f + __expf(-go[k]));
        float e = __expf(-2.f * fabsf(gg[k]));
        float tg = (1.f - e) / (1.f + e); tg = gg[k] < 0.f ? -tg : tg;
        const float cv = sf * cp[k] + si * tg;
        e = __expf(-2.f * fabsf(cv));
        float tc = (1.f - e) / (1.f + e); tc = cv < 0.f ? -tc : tc;
        cn[k] = cv;
        hn[k] = so * tc;
    }
    *(float4*)(c + co) = *(const float4*)cn;
    f16x4 hhi, hlo;
    #pragma unroll
    for (int k = 0; k < 4; ++k) {
        hhi[k] = (_Float16)hn[k];
        hlo[k] = (_Float16)(hn[k] - (float)hhi[k]);
    }
    *(f16x4*)(h + (long)b*2048 + j4)        = hhi;
    *(f16x4*)(h + (long)b*2048 + 1024 + j4) = hlo;
}

// ugate = sum of 4 partials + bias (per column n%4096).  grid 512 x 256.
__global__ __launch_bounds__(256)
void reduce4_bias(const float* __restrict__ part, const float* __restrict__ bias,
                  float* __restrict__ out)
{
    const int t = blockIdx.x * 256 + threadIdx.x;
    const long o = (long)t * 4;
    const int j = (int)(o & 4095);
    float4 s = *(const float4*)(part + o);
    #pragma unroll
    for (int p = 1; p < 4; ++p) {
        const float4 v = *(const float4*)(part + (long)p*524288 + o);
        s.x += v.x; s.y += v.y; s.z += v.z; s.w += v.w;
    }
    const float4 bb = *(const float4*)(bias + j);
    s.x += bb.x; s.y += bb.y; s.z += bb.z; s.w += bb.w;
    *(float4*)(out + o) = s;
}

// ---------------------------------------------------------------------------
// Head: per-row argmax (first-max tie-break) + logsumexp + per-row loss.
// ---------------------------------------------------------------------------
__global__ __launch_bounds__(256)
void head_kernel(const float* __restrict__ logits, const int* __restrict__ act,
                 float* __restrict__ d_out, float* __restrict__ lossbuf)
{
    const int b = blockIdx.x;
    const int tid = threadIdx.x;
    const float* row = logits + (long)b * 1000;

    float mx = -1e30f; int mi = 1 << 30;
    for (int j = tid; j < 1000; j += 256) {
        const float v = row[j];
        if (v > mx) { mx = v; mi = j; }
    }
    __shared__ float smx[256];
    __shared__ int   smi[256];
    smx[tid] = mx; smi[tid] = mi;
    __syncthreads();
    for (int s = 128; s > 0; s >>= 1) {
        if (tid < s) {
            const float v2 = smx[tid + s]; const int i2 = smi[tid + s];
            if (v2 > smx[tid] || (v2 == smx[tid] && i2 < smi[tid])) {
                smx[tid] = v2; smi[tid] = i2;
            }
        }
        __syncthreads();
    }
    const float gmx = smx[0];
    const int   gmi = smi[0];
    __syncthreads();

    float partial = 0.f;
    for (int j = tid; j < 1000; j += 256) partial += __expf(row[j] - gmx);
    smx[tid] = partial;
    __syncthreads();
    for (int s = 128; s > 0; s >>= 1) {
        if (tid < s) smx[tid] += smx[tid + s];
        __syncthreads();
    }
    if (tid == 0) {
        d_out[128000 + b] = (float)gmi;
        lossbuf[b] = gmx + logf(smx[0]) - row[act[b]];
    }
}

__global__ __launch_bounds__(128)
void loss_reduce(const float* __restrict__ lossbuf, float* __restrict__ d_out)
{
    __shared__ float s[128];
    const int tid = threadIdx.x;
    s[tid] = lossbuf[tid];
    __syncthreads();
    for (int k = 64; k > 0; k >>= 1) {
        if (tid < k) s[tid] += s[tid + k];
        __syncthreads();
    }
    if (tid == 0) d_out[128128] = s[0] / 128.f;
}

// ---------------------------------------------------------------------------
extern "C" void kernel_launch(void* const* d_in, const int* in_sizes, int n_in,
                              void* d_out, int out_size, void* d_ws, size_t ws_size,
                              hipStream_t stream)
{
    const float* feats    = (const float*)d_in[0];
    const float* lh       = (const float*)d_in[1];
    const float* rh       = (const float*)d_in[2];
    const int*   act      = (const int*)  d_in[3];
    const float* fc1_w    = (const float*)d_in[4];
    const float* fc1_b    = (const float*)d_in[5];
    const float* fch_w    = (const float*)d_in[6];
    const float* fch_b    = (const float*)d_in[7];
    const float* roll_wih = (const float*)d_in[8];
    const float* roll_whh = (const float*)d_in[9];
    const float* roll_bih = (const float*)d_in[10];
    const float* roll_bhh = (const float*)d_in[11];
    const float* un_wih   = (const float*)d_in[12];
    const float* un_whh   = (const float*)d_in[13];
    const float* un_bih   = (const float*)d_in[14];
    const float* un_bhh   = (const float*)d_in[15];
    const float* cls_w    = (const float*)d_in[16];
    const float* cls_b    = (const float*)d_in[17];

    float* out = (float*)d_out;
    char* ws = (char*)d_ws;
    size_t o = 0;
    auto alloc = [&](size_t b) { size_t r = o; o += (b + 255) & ~(size_t)255; return r; };

    _Float16* x_h2     = (_Float16*)(ws + alloc(2048ul*4096*2));   // x split [hi|lo]
    _Float16* feats_h2 = (_Float16*)(ws + alloc(2048ul*4096*2));   // dead after xproj
    _Float16* wihr_h2  = (_Float16*)(ws + alloc(4096ul*4096*2));
    _Float16* whhr_h2  = (_Float16*)(ws + alloc(4096ul*2048*2));
    float*    xgates   = (float*)   (ws + alloc(16ul*128*4096*4));
    float*    c_st     = (float*)   (ws + alloc(128ul*1024*4));
    _Float16* h_h2     = (_Float16*)(ws + alloc(128ul*2048*2));
    float*    rollb    = (float*)   (ws + alloc(4096*4));
    float*    unb      = (float*)   (ws + alloc(4096*4));
    float*    lossbuf  = (float*)   (ws + alloc(128*4));
    // part (8.39MB) + ugate (2.1MB) alias feats_h2 (16.78MB, dead after xproj)
    float*    part     = (float*)feats_h2;
    float*    ugate    = part + 4ul*128*4096;

    convert_split<<<16384, 256, 0, stream>>>(feats, roll_wih, roll_whh,
                                             feats_h2, wihr_h2, whhr_h2);
    bias_sum<<<16, 256, 0, stream>>>(roll_bih, roll_bhh, un_bih, un_bhh, rollb, unb);
    hipMemsetAsync(c_st, 0, 128ul*1024*4, stream);

    // x[:, :1024] = feats @ fc1_w^T + fc1_b  (M=2048, N=1024, K=2048, W f32 otf)
    gemm_mfma<64, 1, true, true><<<dim3(16, 16, 1), 256, 0, stream>>>(
        feats_h2, 4096, 2048, fc1_w, 2048, 0, fc1_b, x_h2, 4096, 1024, 2048, 0);
    // x[:, 1024:]
    hproj_kernel<<<128, 256, 0, stream>>>(lh, rh, fch_w, fch_b, x_h2);

    // xgates = x @ roll_wih^T + (bih+bhh)  (M=2048, N=4096, K=2048)
    gemm_mfma<128, 0, true, false><<<dim3(32, 16, 1), 256, 0, stream>>>(
        x_h2, 4096, 2048, wihr_h2, 4096, 2048, rollb, xgates, 4096, 4096, 2048, 0);

    // rolling LSTM: 16 sequential steps of h @ roll_whh^T (K=1024, split 4)
    for (int t = 0; t < 16; ++t) {
        gemm_mfma<64, 0, false, false><<<dim3(64, 1, 4), 256, 0, stream>>>(
            h_h2, 2048, 1024, whhr_h2, 2048, 1024, nullptr,
            part, 4096, 4096, 256, 524288);
        lstm_cell4<<<128, 256, 0, stream>>>(part, xgates + (long)t*128*4096, c_st, h_h2);
    }

    // ugate = x[15] @ un_wih^T + (un_bih+un_bhh)   (W f32 otf, K=2048 split 4)
    gemm_mfma<64, 0, false, true><<<dim3(64, 1, 4), 256, 0, stream>>>(
        x_h2 + 15l*128*4096, 4096, 2048, un_wih, 2048, 0, nullptr,
        part, 4096, 4096, 512, 524288);
    reduce4_bias<<<512, 256, 0, stream>>>(part, unb, ugate);

    // two unroll steps (h_n[S-1] = h after 2 steps)
    for (int s2 = 0; s2 < 2; ++s2) {
        gemm_mfma<64, 0, false, true><<<dim3(64, 1, 4), 256, 0, stream>>>(
            h_h2, 2048, 1024, un_whh, 1024, 0, nullptr,
            part, 4096, 4096, 256, 524288);
        lstm_cell4<<<128, 256, 0, stream>>>(part, ugate, c_st, h_h2);
    }

    // classifier: out = h @ cls_w^T + cls_b  (W f32 otf, N=1000)
    gemm_mfma<64, 0, true, true><<<dim3(16, 1, 1), 256, 0, stream>>>(
        h_h2, 2048, 1024, cls_w, 1024, 0, cls_b, out, 1000, 1000, 1024, 0);

    head_kernel<<<128, 256, 0, stream>>>(out, act, out, lossbuf);
    loss_reduce<<<1, 128, 0, stream>>>(lossbuf, out);
}